// Round 5
// baseline (497.952 us; speedup 1.0000x reference)
//
#include <hip/hip_runtime.h>

// Problem constants
#define NB 32
#define NS 2048
#define ND 512
#define NFF 512
#define SCALE 0.044194173824159216f
#define PARTS 32            // blocks per batch
#define ROWSB 64            // x rows per block (PARTS*ROWSB = NS)
#define FPB   16            // output features per block (PARTS*FPB = NFF)
#define GRID (NB * PARTS)   // 1024

// Workspace float offsets. [0, ZERO_FLOATS) zeroed by one hipMemsetAsync.
#define OFF_XW  0           // 16384 (atomic accum, P1)
#define OFF_XT  16384       // 16384 (atomic accum, P3)
#define OFF_ST  32768       // 32    (atomic accum, P3)
#define OFF_WQS 32800       // 16384 (atomic accum, P2)
#define OFF_CB2 49184       // 32    (atomic accum, P2)
#define OFF_D1  49216       // 32 u32 done counters
#define OFF_D2  49248       // 32
#define OFF_D3  49280       // 32
#define ZERO_FLOATS 49312   // ~197 KB

__device__ __forceinline__ float dot4(float4 a, float4 b) {
    return a.x * b.x + a.y * b.y + a.z * b.z + a.w * b.w;
}

__device__ __forceinline__ float wave_reduce(float p) {
#pragma unroll
    for (int m = 1; m < 64; m <<= 1) p += __shfl_xor(p, m, 64);
    return p;
}

__device__ __forceinline__ void reduce2(float& p0, float& p1) {
#pragma unroll
    for (int m = 1; m < 64; m <<= 1) {
        p0 += __shfl_xor(p0, m, 64);
        p1 += __shfl_xor(p1, m, 64);
    }
}

__device__ __forceinline__ void reduce4(float& p0, float& p1, float& p2, float& p3) {
#pragma unroll
    for (int m = 1; m < 64; m <<= 1) {
        p0 += __shfl_xor(p0, m, 64);
        p1 += __shfl_xor(p1, m, 64);
        p2 += __shfl_xor(p2, m, 64);
        p3 += __shfl_xor(p3, m, 64);
    }
}

// Coherent (sc-flagged) load: reads the coherence point where device-scope
// atomics landed. No L2 writeback/invalidate needed. (Protocol passed r4.)
__device__ __forceinline__ float coh_loadf(const float* p) {
    unsigned u = __hip_atomic_load((unsigned*)p, __ATOMIC_RELAXED,
                                   __HIP_MEMORY_SCOPE_AGENT);
    return __uint_as_float(u);
}

// Per-batch barrier: PARTS arrivals on done[b]; every block spins via t0.
// Writers drained their atomics (vmcnt(0) + __syncthreads) before arriving,
// so ctr==PARTS implies all batch data is complete at the coherence point.
// Bounded spin: a bug becomes a visible wrong answer, never a hang.
__device__ __forceinline__ void batch_barrier(unsigned* ctr) {
    asm volatile("s_waitcnt vmcnt(0)" ::: "memory");
    __syncthreads();
    if (threadIdx.x == 0) {
        __hip_atomic_fetch_add(ctr, 1u, __ATOMIC_RELAXED,
                               __HIP_MEMORY_SCOPE_AGENT);
        long spin = 0;
        while (__hip_atomic_load(ctr, __ATOMIC_RELAXED,
                                 __HIP_MEMORY_SCOPE_AGENT) < PARTS) {
            __builtin_amdgcn_s_sleep(2);
            if (++spin > (1L << 20)) break;
        }
    }
    __syncthreads();
}

// ---- Fused kernel: per-batch pipeline, 3 per-batch barriers ---------------
__global__ void __launch_bounds__(256, 4)
k_fused(const float* __restrict__ x, const float* __restrict__ Wq,
        const float* __restrict__ bq, const float* __restrict__ Wk,
        const float* __restrict__ bk, const float* __restrict__ Wv,
        const float* __restrict__ bv, const float* __restrict__ Wt,
        const float* __restrict__ bt, float* __restrict__ out,
        float* __restrict__ ws) {
    float* xw  = ws + OFF_XW;
    float* xt  = ws + OFF_XT;
    float* st  = ws + OFF_ST;
    float* wqs = ws + OFF_WQS;
    float* cb2 = ws + OFF_CB2;
    unsigned* d1 = (unsigned*)(ws + OFF_D1);
    unsigned* d2 = (unsigned*)(ws + OFF_D2);
    unsigned* d3 = (unsigned*)(ws + OFF_D3);

    const int blk  = blockIdx.x;
    const int b    = blk >> 5;
    const int part = blk & 31;
    const int s0   = part * ROWSB;
    const int t    = threadIdx.x;
    const int wv   = t >> 6;
    const int lane = t & 63;

    __shared__ __align__(16) float4 sh0[4][64];   // P1 reduce + P3 combine
    __shared__ __align__(16) float4 sh1[4][64];
    __shared__ __align__(16) float sbuf[ND];      // staged xw / wqs / xt
    __shared__ float skw[FPB];
    __shared__ float sred[4];
    __shared__ float sW[4];
    __shared__ float sscal;

    const float4* xb = (const float4*)(x + (size_t)b * NS * ND);

    // ================= P1: xw[b,:] += sum_{s in slice} Wt[s]*x[b,s,:] ======
    {
        const int col = t & 127;
        const int half = t >> 7;
        float4 acc = make_float4(0.f, 0.f, 0.f, 0.f);
#pragma unroll 8
        for (int i = 0; i < 32; i++) {
            int s = s0 + half + 2 * i;
            float w = Wt[s];
            float4 v = xb[(size_t)s * 128 + col];
            acc.x += w * v.x; acc.y += w * v.y;
            acc.z += w * v.z; acc.w += w * v.w;
        }
        float4* red = (float4*)sh0;
        if (half == 1) red[col] = acc;
        __syncthreads();
        if (half == 0) {
            float4 o = red[col];
            float* dst = xw + b * ND + col * 4;
            atomicAdd(dst + 0, o.x + acc.x);
            atomicAdd(dst + 1, o.y + acc.y);
            atomicAdd(dst + 2, o.z + acc.z);
            atomicAdd(dst + 3, o.w + acc.w);
        }
    }
    batch_barrier(&d1[b]);

    // ================= P2: 16 kwS values; wqs/cb2 contributions ============
    {
        sbuf[t]       = coh_loadf(xw + b * ND + t);
        sbuf[256 + t] = coh_loadf(xw + b * ND + 256 + t);
        float a = 0.f;                       // sw = sum(Wt), redundant/cheap
#pragma unroll
        for (int i = 0; i < 8; i++) a += Wt[t + 256 * i];
        a = wave_reduce(a);
        if (lane == 0) sred[wv] = a;
        __syncthreads();
        const float sw = sred[0] + sred[1] + sred[2] + sred[3];
        const float4* xa4 = (const float4*)sbuf;
        const float4 xa = xa4[lane];
        const float4 xc = xa4[64 + lane];
        const int fb = part * FPB;
        const int f = fb + wv * 4;
        const float4* r0 = (const float4*)(Wk + (size_t)f * ND);
        const float4* r1 = (const float4*)(Wk + (size_t)(f + 1) * ND);
        const float4* r2 = (const float4*)(Wk + (size_t)(f + 2) * ND);
        const float4* r3 = (const float4*)(Wk + (size_t)(f + 3) * ND);
        float p0 = dot4(xa, r0[lane]) + dot4(xc, r0[64 + lane]);
        float p1 = dot4(xa, r1[lane]) + dot4(xc, r1[64 + lane]);
        float p2 = dot4(xa, r2[lane]) + dot4(xc, r2[64 + lane]);
        float p3 = dot4(xa, r3[lane]) + dot4(xc, r3[64 + lane]);
        reduce4(p0, p1, p2, p3);
        if (lane == 0) {
            float k0 = SCALE * (p0 + bk[f]     * sw);
            float k1 = SCALE * (p1 + bk[f + 1] * sw);
            float k2 = SCALE * (p2 + bk[f + 2] * sw);
            float k3 = SCALE * (p3 + bk[f + 3] * sw);
            skw[wv * 4 + 0] = k0; skw[wv * 4 + 1] = k1;
            skw[wv * 4 + 2] = k2; skw[wv * 4 + 3] = k3;
            sW[wv] = k0 * bq[f] + k1 * bq[f + 1]
                   + k2 * bq[f + 2] + k3 * bq[f + 3];
        }
        __syncthreads();
        float a0 = 0.f, a1 = 0.f;
#pragma unroll
        for (int j = 0; j < FPB; j++) {
            float kf = skw[j];
            const float* wr = Wq + (size_t)(fb + j) * ND;
            a0 += kf * wr[t];
            a1 += kf * wr[256 + t];
        }
        atomicAdd(&wqs[b * ND + t], a0);
        atomicAdd(&wqs[b * ND + 256 + t], a1);
        if (t == 0) {
            float cb = sW[0] + sW[1] + sW[2] + sW[3];
            if (part == 0) cb += bt[0];
            atomicAdd(&cb2[b], cb);
        }
    }
    batch_barrier(&d2[b]);

    // ================= P3: ta = x.wqs + cb2; xt/st accumulation ============
    {
        sbuf[t]       = coh_loadf(wqs + b * ND + t);
        sbuf[256 + t] = coh_loadf(wqs + b * ND + 256 + t);
        if (t == 0) sscal = coh_loadf(cb2 + b);
        __syncthreads();
        const float4* wq4 = (const float4*)sbuf;
        const float4 w0 = wq4[lane];
        const float4 w1 = wq4[64 + lane];
        const float c = sscal;
        float4 a0 = make_float4(0.f, 0.f, 0.f, 0.f);
        float4 a1 = make_float4(0.f, 0.f, 0.f, 0.f);
        float sta = 0.f;
#pragma unroll
        for (int g = 0; g < 8; g++) {
            int s = s0 + wv * 16 + 2 * g;
            float4 u0 = xb[(size_t)s * 128 + lane];
            float4 u1 = xb[(size_t)s * 128 + 64 + lane];
            float4 v0 = xb[(size_t)(s + 1) * 128 + lane];
            float4 v1 = xb[(size_t)(s + 1) * 128 + 64 + lane];
            float pa = dot4(u0, w0) + dot4(u1, w1);
            float pb = dot4(v0, w0) + dot4(v1, w1);
            reduce2(pa, pb);
            float taa = pa + c;
            float tab = pb + c;
            a0.x += taa * u0.x + tab * v0.x; a0.y += taa * u0.y + tab * v0.y;
            a0.z += taa * u0.z + tab * v0.z; a0.w += taa * u0.w + tab * v0.w;
            a1.x += taa * u1.x + tab * v1.x; a1.y += taa * u1.y + tab * v1.y;
            a1.z += taa * u1.z + tab * v1.z; a1.w += taa * u1.w + tab * v1.w;
            sta += taa + tab;
        }
        __syncthreads();   // sbuf reads done before sh0/sh1 reuse below
        sh0[wv][lane] = a0;
        sh1[wv][lane] = a1;
        if (lane == 0) sW[wv] = sta;
        __syncthreads();
        float* xbt = xt + b * ND;
        if (t < 64) {
            float4 q0 = sh0[0][t], q1 = sh0[1][t], q2 = sh0[2][t], q3 = sh0[3][t];
            atomicAdd(&xbt[4 * t + 0], q0.x + q1.x + q2.x + q3.x);
            atomicAdd(&xbt[4 * t + 1], q0.y + q1.y + q2.y + q3.y);
            atomicAdd(&xbt[4 * t + 2], q0.z + q1.z + q2.z + q3.z);
            atomicAdd(&xbt[4 * t + 3], q0.w + q1.w + q2.w + q3.w);
        } else if (t < 128) {
            int l = t - 64;
            float4 q0 = sh1[0][l], q1 = sh1[1][l], q2 = sh1[2][l], q3 = sh1[3][l];
            atomicAdd(&xbt[256 + 4 * l + 0], q0.x + q1.x + q2.x + q3.x);
            atomicAdd(&xbt[256 + 4 * l + 1], q0.y + q1.y + q2.y + q3.y);
            atomicAdd(&xbt[256 + 4 * l + 2], q0.z + q1.z + q2.z + q3.z);
            atomicAdd(&xbt[256 + 4 * l + 3], q0.w + q1.w + q2.w + q3.w);
        } else if (t == 128) {
            atomicAdd(&st[b], sW[0] + sW[1] + sW[2] + sW[3]);
        }
    }
    batch_barrier(&d3[b]);

    // ================= P4: out[b, f-slice] = Wv.xt + bv*st =================
    {
        sbuf[t]       = coh_loadf(xt + b * ND + t);
        sbuf[256 + t] = coh_loadf(xt + b * ND + 256 + t);
        if (t == 0) sscal = coh_loadf(st + b);
        __syncthreads();
        const float4* xa4 = (const float4*)sbuf;
        const float4 xa = xa4[lane];
        const float4 xc = xa4[64 + lane];
        const float stb = sscal;
        const int f = part * FPB + wv * 4;
        const float4* r0 = (const float4*)(Wv + (size_t)f * ND);
        const float4* r1 = (const float4*)(Wv + (size_t)(f + 1) * ND);
        const float4* r2 = (const float4*)(Wv + (size_t)(f + 2) * ND);
        const float4* r3 = (const float4*)(Wv + (size_t)(f + 3) * ND);
        float p0 = dot4(xa, r0[lane]) + dot4(xc, r0[64 + lane]);
        float p1 = dot4(xa, r1[lane]) + dot4(xc, r1[64 + lane]);
        float p2 = dot4(xa, r2[lane]) + dot4(xc, r2[64 + lane]);
        float p3 = dot4(xa, r3[lane]) + dot4(xc, r3[64 + lane]);
        reduce4(p0, p1, p2, p3);
        if (lane == 0) {
            out[b * NFF + f]     = p0 + bv[f]     * stb;
            out[b * NFF + f + 1] = p1 + bv[f + 1] * stb;
            out[b * NFF + f + 2] = p2 + bv[f + 2] * stb;
            out[b * NFF + f + 3] = p3 + bv[f + 3] * stb;
        }
    }
}

extern "C" void kernel_launch(void* const* d_in, const int* in_sizes, int n_in,
                              void* d_out, int out_size, void* d_ws, size_t ws_size,
                              hipStream_t stream) {
    const float* x  = (const float*)d_in[0];
    const float* Wq = (const float*)d_in[1];
    const float* bq = (const float*)d_in[2];
    const float* Wk = (const float*)d_in[3];
    const float* bk = (const float*)d_in[4];
    const float* Wv = (const float*)d_in[5];
    const float* bv = (const float*)d_in[6];
    const float* Wt = (const float*)d_in[7];
    const float* bt = (const float*)d_in[8];
    float* out = (float*)d_out;
    float* ws = (float*)d_ws;

    // zero accumulators + done counters (workspace poisoned per iteration)
    hipMemsetAsync(ws, 0, ZERO_FLOATS * sizeof(float), stream);
    k_fused<<<GRID, 256, 0, stream>>>(x, Wq, bq, Wk, bk, Wv, bv, Wt, bt, out, ws);
}

// Round 6
// 278.797 us; speedup vs baseline: 1.7861x; 1.7861x over previous
//
#include <hip/hip_runtime.h>

// Problem constants
#define NB 32
#define NS 2048
#define ND 512
#define NFF 512
#define SCALE 0.044194173824159216f
#define CPB 64
#define ROWS 32

__device__ __forceinline__ float dot4(float4 a, float4 b) {
    return a.x * b.x + a.y * b.y + a.z * b.z + a.w * b.w;
}

__device__ __forceinline__ float wave_reduce(float p) {
#pragma unroll
    for (int m = 1; m < 64; m <<= 1) p += __shfl_xor(p, m, 64);
    return p;
}

__device__ __forceinline__ void reduce4(float& p0, float& p1, float& p2, float& p3) {
#pragma unroll
    for (int m = 1; m < 64; m <<= 1) {
        p0 += __shfl_xor(p0, m, 64);
        p1 += __shfl_xor(p1, m, 64);
        p2 += __shfl_xor(p2, m, 64);
        p3 += __shfl_xor(p3, m, 64);
    }
}

// ---- K1: xwp[blk][d] = sum_{s in chunk} Wt[s]*x[b,s,d]  (pass 1) ----------
// grid = NB*64 = 2048 blocks, 256 threads. Pure partials, no atomics.
__global__ void __launch_bounds__(256) k_xw(const float* __restrict__ x,
                                            const float* __restrict__ Wt,
                                            float* __restrict__ xwp) {
    const int b = blockIdx.x >> 6;
    const int chunk = blockIdx.x & 63;
    const int s0 = chunk * ROWS;
    const int t = threadIdx.x;
    const int col = t & 127;   // float4 column
    const int half = t >> 7;   // row interleave (0/1)

    const float4* xb = (const float4*)(x + (size_t)b * NS * ND);
    float4 acc = make_float4(0.f, 0.f, 0.f, 0.f);
#pragma unroll 4
    for (int i = 0; i < 16; i++) {
        int s = s0 + half + 2 * i;
        float w = Wt[s];
        float4 v = xb[(size_t)s * 128 + col];
        acc.x += w * v.x; acc.y += w * v.y; acc.z += w * v.z; acc.w += w * v.w;
    }
    __shared__ float4 red[128];
    if (half == 1) red[col] = acc;
    __syncthreads();
    if (half == 0) {
        float4 o = red[col];
        o.x += acc.x; o.y += acc.y; o.z += acc.z; o.w += acc.w;
        ((float4*)xwp)[(size_t)blockIdx.x * 128 + col] = o;
    }
}

// ---- K2: per batch b (one 1024-thread block):
//   xw = sum_c xwp[b,c,:];  kw[f] = SCALE*(Wk[f,:].xw + bk[f]*sum(Wt));
//   wqs[b,d] = sum_f kw[f]*Wq[f,d];  cb2[b] = kw.bq + bt
__global__ void __launch_bounds__(1024, 1)
k_mid(const float* __restrict__ xwp, const float* __restrict__ Wt,
      const float* __restrict__ Wk, const float* __restrict__ bk,
      const float* __restrict__ Wq, const float* __restrict__ bq,
      const float* __restrict__ bt, float* __restrict__ wqs,
      float* __restrict__ cb2) {
    const int b = blockIdx.x;
    const int t = threadIdx.x;
    const int c4 = t & 127;    // float4 column of d
    const int grp = t >> 7;    // 8 groups
    __shared__ __align__(16) float4 tmp4[1024];
    __shared__ __align__(16) float sxw[ND];
    __shared__ float skw[NFF];
    __shared__ float sW[16];
    __shared__ float ssw;

    // Stage 1: reduce the 64 xwp chunks (each group sums 8 chunks)
    {
        const float4* xp = (const float4*)(xwp + (size_t)b * CPB * ND) + c4;
        float4 a = make_float4(0.f, 0.f, 0.f, 0.f);
#pragma unroll
        for (int c = 0; c < 8; c++) {
            float4 v = xp[(size_t)(grp * 8 + c) * 128];
            a.x += v.x; a.y += v.y; a.z += v.z; a.w += v.w;
        }
        tmp4[t] = a;
    }
    if (t < 64) {   // sw = sum(Wt), wave 0, overlapped
        float s = 0.f;
#pragma unroll
        for (int i = 0; i < 32; i++) s += Wt[t + 64 * i];
        s = wave_reduce(s);
        if (t == 0) ssw = s;
    }
    __syncthreads();
    if (t < 128) {
        float4 a = tmp4[t];
#pragma unroll
        for (int g = 1; g < 8; g++) {
            float4 v = tmp4[g * 128 + t];
            a.x += v.x; a.y += v.y; a.z += v.z; a.w += v.w;
        }
        ((float4*)sxw)[t] = a;
    }
    __syncthreads();

    // Stage 2: kw GEMV, 16 waves x 32 f, ILP-4
    const int wv = t >> 6;
    const int lane = t & 63;
    const float sw = ssw;
    const float4 xa = ((const float4*)sxw)[lane];
    const float4 xc = ((const float4*)sxw)[64 + lane];
    float cbp = 0.f;
#pragma unroll
    for (int j = 0; j < 8; j++) {
        const int f = wv * 32 + j * 4;
        const float4* r0 = (const float4*)(Wk + (size_t)f * ND);
        const float4* r1 = (const float4*)(Wk + (size_t)(f + 1) * ND);
        const float4* r2 = (const float4*)(Wk + (size_t)(f + 2) * ND);
        const float4* r3 = (const float4*)(Wk + (size_t)(f + 3) * ND);
        float p0 = dot4(xa, r0[lane]) + dot4(xc, r0[64 + lane]);
        float p1 = dot4(xa, r1[lane]) + dot4(xc, r1[64 + lane]);
        float p2 = dot4(xa, r2[lane]) + dot4(xc, r2[64 + lane]);
        float p3 = dot4(xa, r3[lane]) + dot4(xc, r3[64 + lane]);
        reduce4(p0, p1, p2, p3);
        if (lane == 0) {
            float k0 = SCALE * (p0 + bk[f]     * sw);
            float k1 = SCALE * (p1 + bk[f + 1] * sw);
            float k2 = SCALE * (p2 + bk[f + 2] * sw);
            float k3 = SCALE * (p3 + bk[f + 3] * sw);
            skw[f] = k0; skw[f + 1] = k1; skw[f + 2] = k2; skw[f + 3] = k3;
            cbp += k0 * bq[f] + k1 * bq[f + 1] + k2 * bq[f + 2] + k3 * bq[f + 3];
        }
    }
    if (lane == 0) sW[wv] = cbp;
    __syncthreads();

    // Stage 3: wqs[d] = sum_f skw[f]*Wq[f,d] (each group covers 64 f)
    {
        float4 acc = make_float4(0.f, 0.f, 0.f, 0.f);
        const float4* wq4 = (const float4*)Wq + c4;   // row stride = 128 f4
#pragma unroll 4
        for (int j = 0; j < 64; j++) {
            int f = grp * 64 + j;
            float kf = skw[f];
            float4 v = wq4[(size_t)f * 128];
            acc.x += kf * v.x; acc.y += kf * v.y;
            acc.z += kf * v.z; acc.w += kf * v.w;
        }
        tmp4[t] = acc;
    }
    __syncthreads();
    if (t < 128) {
        float4 a = tmp4[t];
#pragma unroll
        for (int g = 1; g < 8; g++) {
            float4 v = tmp4[g * 128 + t];
            a.x += v.x; a.y += v.y; a.z += v.z; a.w += v.w;
        }
        ((float4*)(wqs + b * ND))[t] = a;
    }
    if (t == 0) {
        float cb = 0.f;
#pragma unroll
        for (int i = 0; i < 16; i++) cb += sW[i];
        cb2[b] = cb + bt[0];
    }
}

// ---- K3: ta = x.wqs + cb2; xtp[blk][d] = sum_s ta*x; stp[blk] (pass 2) ----
// grid = 2048 blocks (32 rows), 256 threads = 4 waves, 8 rows/wave.
// 8-way ILP across the per-row shuffle reduction trees. (Proven in r1.)
__global__ void __launch_bounds__(256) k_ta_xt(const float* __restrict__ x,
                                               const float* __restrict__ wqs,
                                               const float* __restrict__ cb2,
                                               float* __restrict__ xtp,
                                               float* __restrict__ stp) {
    const int b = blockIdx.x >> 6;
    const int chunk = blockIdx.x & 63;
    const int wv = threadIdx.x >> 6;
    const int lane = threadIdx.x & 63;
    const float4* xb = (const float4*)(x + (size_t)b * NS * ND);
    const float4* wq4 = (const float4*)(wqs + b * ND);
    const float4 w0 = wq4[lane];
    const float4 w1 = wq4[64 + lane];
    const float c = cb2[b];

    float4 v0[8], v1[8];
    float pd[8];
#pragma unroll
    for (int i = 0; i < 8; i++) {
        int s = chunk * ROWS + wv * 8 + i;
        v0[i] = xb[(size_t)s * 128 + lane];
        v1[i] = xb[(size_t)s * 128 + 64 + lane];
        pd[i] = dot4(v0[i], w0) + dot4(v1[i], w1);
    }
#pragma unroll
    for (int m = 1; m < 64; m <<= 1) {
#pragma unroll
        for (int i = 0; i < 8; i++) pd[i] += __shfl_xor(pd[i], m, 64);
    }
    float4 a0 = make_float4(0.f, 0.f, 0.f, 0.f);
    float4 a1 = make_float4(0.f, 0.f, 0.f, 0.f);
    float sta = 0.f;
#pragma unroll
    for (int i = 0; i < 8; i++) {
        float ta = pd[i] + c;
        a0.x += ta * v0[i].x; a0.y += ta * v0[i].y; a0.z += ta * v0[i].z; a0.w += ta * v0[i].w;
        a1.x += ta * v1[i].x; a1.y += ta * v1[i].y; a1.z += ta * v1[i].z; a1.w += ta * v1[i].w;
        sta += ta;
    }
    __shared__ float4 sh0[4][64];
    __shared__ float4 sh1[4][64];
    __shared__ float sW[4];
    sh0[wv][lane] = a0;
    sh1[wv][lane] = a1;
    if (lane == 0) sW[wv] = sta;
    __syncthreads();
    const int t = threadIdx.x;
    float4* dst = (float4*)xtp + (size_t)blockIdx.x * 128;
    if (t < 64) {
        float4 s0 = sh0[0][t], s1 = sh0[1][t], s2 = sh0[2][t], s3 = sh0[3][t];
        dst[t] = make_float4(s0.x + s1.x + s2.x + s3.x,
                             s0.y + s1.y + s2.y + s3.y,
                             s0.z + s1.z + s2.z + s3.z,
                             s0.w + s1.w + s2.w + s3.w);
    } else if (t < 128) {
        int l = t - 64;
        float4 s0 = sh1[0][l], s1 = sh1[1][l], s2 = sh1[2][l], s3 = sh1[3][l];
        dst[64 + l] = make_float4(s0.x + s1.x + s2.x + s3.x,
                                  s0.y + s1.y + s2.y + s3.y,
                                  s0.z + s1.z + s2.z + s3.z,
                                  s0.w + s1.w + s2.w + s3.w);
    } else if (t == 128) {
        stp[blockIdx.x] = sW[0] + sW[1] + sW[2] + sW[3];
    }
}

// ---- K4: per batch b (one 1024-thread block):
//   xt = sum_c xtp[b,c,:]; st = sum stp[b,:]; out[b,f] = Wv[f,:].xt + bv[f]*st
__global__ void __launch_bounds__(1024, 1)
k_fin(const float* __restrict__ xtp, const float* __restrict__ stp,
      const float* __restrict__ Wv, const float* __restrict__ bv,
      float* __restrict__ out) {
    const int b = blockIdx.x;
    const int t = threadIdx.x;
    const int c4 = t & 127;
    const int grp = t >> 7;
    __shared__ __align__(16) float4 tmp4[1024];
    __shared__ __align__(16) float sxt[ND];
    __shared__ float sst;

    {
        const float4* xp = (const float4*)(xtp + (size_t)b * CPB * ND) + c4;
        float4 a = make_float4(0.f, 0.f, 0.f, 0.f);
#pragma unroll
        for (int c = 0; c < 8; c++) {
            float4 v = xp[(size_t)(grp * 8 + c) * 128];
            a.x += v.x; a.y += v.y; a.z += v.z; a.w += v.w;
        }
        tmp4[t] = a;
    }
    if (t < 64) {
        float s = stp[b * CPB + t];
        s = wave_reduce(s);
        if (t == 0) sst = s;
    }
    __syncthreads();
    if (t < 128) {
        float4 a = tmp4[t];
#pragma unroll
        for (int g = 1; g < 8; g++) {
            float4 v = tmp4[g * 128 + t];
            a.x += v.x; a.y += v.y; a.z += v.z; a.w += v.w;
        }
        ((float4*)sxt)[t] = a;
    }
    __syncthreads();

    const int wv = t >> 6;
    const int lane = t & 63;
    const float4 xa = ((const float4*)sxt)[lane];
    const float4 xc = ((const float4*)sxt)[64 + lane];
    const float stb = sst;
#pragma unroll
    for (int j = 0; j < 8; j++) {
        const int f = wv * 32 + j * 4;
        const float4* r0 = (const float4*)(Wv + (size_t)f * ND);
        const float4* r1 = (const float4*)(Wv + (size_t)(f + 1) * ND);
        const float4* r2 = (const float4*)(Wv + (size_t)(f + 2) * ND);
        const float4* r3 = (const float4*)(Wv + (size_t)(f + 3) * ND);
        float p0 = dot4(xa, r0[lane]) + dot4(xc, r0[64 + lane]);
        float p1 = dot4(xa, r1[lane]) + dot4(xc, r1[64 + lane]);
        float p2 = dot4(xa, r2[lane]) + dot4(xc, r2[64 + lane]);
        float p3 = dot4(xa, r3[lane]) + dot4(xc, r3[64 + lane]);
        reduce4(p0, p1, p2, p3);
        if (lane == 0) {
            out[b * NFF + f]     = p0 + bv[f]     * stb;
            out[b * NFF + f + 1] = p1 + bv[f + 1] * stb;
            out[b * NFF + f + 2] = p2 + bv[f + 2] * stb;
            out[b * NFF + f + 3] = p3 + bv[f + 3] * stb;
        }
    }
}

extern "C" void kernel_launch(void* const* d_in, const int* in_sizes, int n_in,
                              void* d_out, int out_size, void* d_ws, size_t ws_size,
                              hipStream_t stream) {
    const float* x  = (const float*)d_in[0];
    const float* Wq = (const float*)d_in[1];
    const float* bq = (const float*)d_in[2];
    const float* Wk = (const float*)d_in[3];
    const float* bk = (const float*)d_in[4];
    const float* Wv = (const float*)d_in[5];
    const float* bv = (const float*)d_in[6];
    const float* Wt = (const float*)d_in[7];
    const float* bt = (const float*)d_in[8];
    float* out = (float*)d_out;

    float* w = (float*)d_ws;
    float* xwp = w;                  // 2048*512 = 1048576 floats
    float* xtp = w + 1048576;        // 1048576
    float* stp = w + 2097152;        // 2048
    float* wqs = w + 2099200;        // 16384
    float* cb2 = w + 2115584;        // 32

    k_xw<<<NB * CPB, 256, 0, stream>>>(x, Wt, xwp);
    k_mid<<<NB, 1024, 0, stream>>>(xwp, Wt, Wk, bk, Wq, bq, bt, wqs, cb2);
    k_ta_xt<<<NB * CPB, 256, 0, stream>>>(x, wqs, cb2, xtp, stp);
    k_fin<<<NB, 1024, 0, stream>>>(xtp, stp, Wv, bv, out);
}

// Round 7
// 276.914 us; speedup vs baseline: 1.7982x; 1.0068x over previous
//
#include <hip/hip_runtime.h>

// Problem constants
#define NB 32
#define NS 2048
#define ND 512
#define NFF 512
#define SCALE 0.044194173824159216f
#define CPB 32          // chunks per batch
#define ROWS 64         // rows per chunk (CPB*ROWS = NS)

__device__ __forceinline__ float dot4(float4 a, float4 b) {
    return a.x * b.x + a.y * b.y + a.z * b.z + a.w * b.w;
}

__device__ __forceinline__ float wave_reduce(float p) {
#pragma unroll
    for (int m = 1; m < 64; m <<= 1) p += __shfl_xor(p, m, 64);
    return p;
}

// ---- K1: xwp[blk][d] = sum_{s in chunk} Wt[s]*x[b,s,d]  (pass 1) ----------
// grid = NB*CPB = 1024 blocks, 256 threads, 64 rows/block. Pure partials.
__global__ void __launch_bounds__(256) k_xw(const float* __restrict__ x,
                                            const float* __restrict__ Wt,
                                            float* __restrict__ xwp) {
    const int b = blockIdx.x >> 5;
    const int chunk = blockIdx.x & 31;
    const int s0 = chunk * ROWS;
    const int t = threadIdx.x;
    const int col = t & 127;   // float4 column
    const int half = t >> 7;   // row interleave (0/1)

    const float4* xb = (const float4*)(x + (size_t)b * NS * ND);
    float4 acc = make_float4(0.f, 0.f, 0.f, 0.f);
#pragma unroll 8
    for (int i = 0; i < 32; i++) {
        int s = s0 + half + 2 * i;
        float w = Wt[s];
        float4 v = xb[(size_t)s * 128 + col];
        acc.x += w * v.x; acc.y += w * v.y; acc.z += w * v.z; acc.w += w * v.w;
    }
    __shared__ float4 red[128];
    if (half == 1) red[col] = acc;
    __syncthreads();
    if (half == 0) {
        float4 o = red[col];
        o.x += acc.x; o.y += acc.y; o.z += acc.z; o.w += acc.w;
        ((float4*)xwp)[(size_t)blockIdx.x * 128 + col] = o;
    }
}

// ---- K2: per batch b (one 1024-thread block):
//   xw = sum_c xwp[b,c,:];  kw[f] = SCALE*(Wk[f,:].xw + bk[f]*sum(Wt));
//   wqs[b,d] = sum_f kw[f]*Wq[f,d];  cb2[b] = kw.bq + bt
__global__ void __launch_bounds__(1024, 1)
k_mid(const float* __restrict__ xwp, const float* __restrict__ Wt,
      const float* __restrict__ Wk, const float* __restrict__ bk,
      const float* __restrict__ Wq, const float* __restrict__ bq,
      const float* __restrict__ bt, float* __restrict__ wqs,
      float* __restrict__ cb2) {
    const int b = blockIdx.x;
    const int t = threadIdx.x;
    const int c4 = t & 127;    // float4 column of d
    const int grp = t >> 7;    // 8 groups
    __shared__ __align__(16) float4 tmp4[1024];
    __shared__ __align__(16) float sxw[ND];
    __shared__ float skw[NFF];
    __shared__ float sW[16];
    __shared__ float ssw;

    // Stage 1: reduce the 32 xwp chunks (each group sums 4 chunks)
    {
        const float4* xp = (const float4*)(xwp + (size_t)b * CPB * ND) + c4;
        float4 a = make_float4(0.f, 0.f, 0.f, 0.f);
#pragma unroll
        for (int c = 0; c < 4; c++) {
            float4 v = xp[(size_t)(grp * 4 + c) * 128];
            a.x += v.x; a.y += v.y; a.z += v.z; a.w += v.w;
        }
        tmp4[t] = a;
    }
    if (t < 64) {   // sw = sum(Wt), wave 0, overlapped
        float s = 0.f;
#pragma unroll
        for (int i = 0; i < 32; i++) s += Wt[t + 64 * i];
        s = wave_reduce(s);
        if (t == 0) ssw = s;
    }
    __syncthreads();
    if (t < 128) {
        float4 a = tmp4[t];
#pragma unroll
        for (int g = 1; g < 8; g++) {
            float4 v = tmp4[g * 128 + t];
            a.x += v.x; a.y += v.y; a.z += v.z; a.w += v.w;
        }
        ((float4*)sxw)[t] = a;
    }
    __syncthreads();

    // Stage 2: kw GEMV, 16 waves x 32 f, ILP-8 interleaved reduction trees
    const int wv = t >> 6;
    const int lane = t & 63;
    const float sw = ssw;
    const float4 xa = ((const float4*)sxw)[lane];
    const float4 xc = ((const float4*)sxw)[64 + lane];
    float cbp = 0.f;
#pragma unroll
    for (int j = 0; j < 4; j++) {
        const int f = wv * 32 + j * 8;
        float p[8];
#pragma unroll
        for (int u = 0; u < 8; u++) {
            const float4* r = (const float4*)(Wk + (size_t)(f + u) * ND);
            p[u] = dot4(xa, r[lane]) + dot4(xc, r[64 + lane]);
        }
#pragma unroll
        for (int m = 1; m < 64; m <<= 1) {
#pragma unroll
            for (int u = 0; u < 8; u++) p[u] += __shfl_xor(p[u], m, 64);
        }
        if (lane == 0) {
#pragma unroll
            for (int u = 0; u < 8; u++) {
                float k = SCALE * (p[u] + bk[f + u] * sw);
                skw[f + u] = k;
                cbp += k * bq[f + u];
            }
        }
    }
    if (lane == 0) sW[wv] = cbp;
    __syncthreads();

    // Stage 3: wqs[d] = sum_f skw[f]*Wq[f,d] (each group covers 64 f)
    {
        float4 acc = make_float4(0.f, 0.f, 0.f, 0.f);
        const float4* wq4 = (const float4*)Wq + c4;   // row stride = 128 f4
#pragma unroll 4
        for (int j = 0; j < 64; j++) {
            int f = grp * 64 + j;
            float kf = skw[f];
            float4 v = wq4[(size_t)f * 128];
            acc.x += kf * v.x; acc.y += kf * v.y;
            acc.z += kf * v.z; acc.w += kf * v.w;
        }
        tmp4[t] = acc;
    }
    __syncthreads();
    if (t < 128) {
        float4 a = tmp4[t];
#pragma unroll
        for (int g = 1; g < 8; g++) {
            float4 v = tmp4[g * 128 + t];
            a.x += v.x; a.y += v.y; a.z += v.z; a.w += v.w;
        }
        ((float4*)(wqs + b * ND))[t] = a;
    }
    if (t == 0) {
        float cb = 0.f;
#pragma unroll
        for (int i = 0; i < 16; i++) cb += sW[i];
        cb2[b] = cb + bt[0];
    }
}

// ---- K3: ta = x.wqs + cb2; xtp[blk][d] = sum_s ta*x; stp[blk] (pass 2) ----
// grid = 1024 blocks (64 rows), 256 threads = 4 waves, 16 rows/wave,
// run as 2 passes of the proven 8-row ILP shuffle-tree body.
__global__ void __launch_bounds__(256) k_ta_xt(const float* __restrict__ x,
                                               const float* __restrict__ wqs,
                                               const float* __restrict__ cb2,
                                               float* __restrict__ xtp,
                                               float* __restrict__ stp) {
    const int b = blockIdx.x >> 5;
    const int chunk = blockIdx.x & 31;
    const int wv = threadIdx.x >> 6;
    const int lane = threadIdx.x & 63;
    const float4* xb = (const float4*)(x + (size_t)b * NS * ND);
    const float4* wq4 = (const float4*)(wqs + b * ND);
    const float4 w0 = wq4[lane];
    const float4 w1 = wq4[64 + lane];
    const float c = cb2[b];

    float4 a0 = make_float4(0.f, 0.f, 0.f, 0.f);
    float4 a1 = make_float4(0.f, 0.f, 0.f, 0.f);
    float sta = 0.f;
#pragma unroll
    for (int pass = 0; pass < 2; pass++) {
        const int sbase = chunk * ROWS + wv * 16 + pass * 8;
        float4 v0[8], v1[8];
        float pd[8];
#pragma unroll
        for (int i = 0; i < 8; i++) {
            int s = sbase + i;
            v0[i] = xb[(size_t)s * 128 + lane];
            v1[i] = xb[(size_t)s * 128 + 64 + lane];
            pd[i] = dot4(v0[i], w0) + dot4(v1[i], w1);
        }
#pragma unroll
        for (int m = 1; m < 64; m <<= 1) {
#pragma unroll
            for (int i = 0; i < 8; i++) pd[i] += __shfl_xor(pd[i], m, 64);
        }
#pragma unroll
        for (int i = 0; i < 8; i++) {
            float ta = pd[i] + c;
            a0.x += ta * v0[i].x; a0.y += ta * v0[i].y;
            a0.z += ta * v0[i].z; a0.w += ta * v0[i].w;
            a1.x += ta * v1[i].x; a1.y += ta * v1[i].y;
            a1.z += ta * v1[i].z; a1.w += ta * v1[i].w;
            sta += ta;
        }
    }
    __shared__ float4 sh0[4][64];
    __shared__ float4 sh1[4][64];
    __shared__ float sW[4];
    sh0[wv][lane] = a0;
    sh1[wv][lane] = a1;
    if (lane == 0) sW[wv] = sta;
    __syncthreads();
    const int t = threadIdx.x;
    float4* dst = (float4*)xtp + (size_t)blockIdx.x * 128;
    if (t < 64) {
        float4 s0 = sh0[0][t], s1 = sh0[1][t], s2 = sh0[2][t], s3 = sh0[3][t];
        dst[t] = make_float4(s0.x + s1.x + s2.x + s3.x,
                             s0.y + s1.y + s2.y + s3.y,
                             s0.z + s1.z + s2.z + s3.z,
                             s0.w + s1.w + s2.w + s3.w);
    } else if (t < 128) {
        int l = t - 64;
        float4 s0 = sh1[0][l], s1 = sh1[1][l], s2 = sh1[2][l], s3 = sh1[3][l];
        dst[64 + l] = make_float4(s0.x + s1.x + s2.x + s3.x,
                                  s0.y + s1.y + s2.y + s3.y,
                                  s0.z + s1.z + s2.z + s3.z,
                                  s0.w + s1.w + s2.w + s3.w);
    } else if (t == 128) {
        stp[blockIdx.x] = sW[0] + sW[1] + sW[2] + sW[3];
    }
}

// ---- K4: per batch b (one 1024-thread block):
//   xt = sum_c xtp[b,c,:]; st = sum stp[b,:]; out[b,f] = Wv[f,:].xt + bv[f]*st
__global__ void __launch_bounds__(1024, 1)
k_fin(const float* __restrict__ xtp, const float* __restrict__ stp,
      const float* __restrict__ Wv, const float* __restrict__ bv,
      float* __restrict__ out) {
    const int b = blockIdx.x;
    const int t = threadIdx.x;
    const int c4 = t & 127;
    const int grp = t >> 7;
    __shared__ __align__(16) float4 tmp4[1024];
    __shared__ __align__(16) float sxt[ND];
    __shared__ float sst;

    {
        const float4* xp = (const float4*)(xtp + (size_t)b * CPB * ND) + c4;
        float4 a = make_float4(0.f, 0.f, 0.f, 0.f);
#pragma unroll
        for (int c = 0; c < 4; c++) {
            float4 v = xp[(size_t)(grp * 4 + c) * 128];
            a.x += v.x; a.y += v.y; a.z += v.z; a.w += v.w;
        }
        tmp4[t] = a;
    }
    if (t < 64) {   // st = sum of 32 chunk partials (lanes >=32 contribute 0)
        float s = (t < CPB) ? stp[b * CPB + t] : 0.f;
        s = wave_reduce(s);
        if (t == 0) sst = s;
    }
    __syncthreads();
    if (t < 128) {
        float4 a = tmp4[t];
#pragma unroll
        for (int g = 1; g < 8; g++) {
            float4 v = tmp4[g * 128 + t];
            a.x += v.x; a.y += v.y; a.z += v.z; a.w += v.w;
        }
        ((float4*)sxt)[t] = a;
    }
    __syncthreads();

    const int wv = t >> 6;
    const int lane = t & 63;
    const float4 xa = ((const float4*)sxt)[lane];
    const float4 xc = ((const float4*)sxt)[64 + lane];
    const float stb = sst;
#pragma unroll
    for (int j = 0; j < 4; j++) {
        const int f = wv * 32 + j * 8;
        float p[8];
#pragma unroll
        for (int u = 0; u < 8; u++) {
            const float4* r = (const float4*)(Wv + (size_t)(f + u) * ND);
            p[u] = dot4(xa, r[lane]) + dot4(xc, r[64 + lane]);
        }
#pragma unroll
        for (int m = 1; m < 64; m <<= 1) {
#pragma unroll
            for (int u = 0; u < 8; u++) p[u] += __shfl_xor(p[u], m, 64);
        }
        if (lane == 0) {
#pragma unroll
            for (int u = 0; u < 8; u++)
                out[b * NFF + f + u] = p[u] + bv[f + u] * stb;
        }
    }
}

extern "C" void kernel_launch(void* const* d_in, const int* in_sizes, int n_in,
                              void* d_out, int out_size, void* d_ws, size_t ws_size,
                              hipStream_t stream) {
    const float* x  = (const float*)d_in[0];
    const float* Wq = (const float*)d_in[1];
    const float* bq = (const float*)d_in[2];
    const float* Wk = (const float*)d_in[3];
    const float* bk = (const float*)d_in[4];
    const float* Wv = (const float*)d_in[5];
    const float* bv = (const float*)d_in[6];
    const float* Wt = (const float*)d_in[7];
    const float* bt = (const float*)d_in[8];
    float* out = (float*)d_out;

    float* w = (float*)d_ws;
    float* xwp = w;                  // 1024*512 = 524288 floats
    float* xtp = w + 524288;         // 524288
    float* stp = w + 1048576;        // 1024
    float* wqs = w + 1049600;        // 16384
    float* cb2 = w + 1065984;        // 32

    k_xw<<<NB * CPB, 256, 0, stream>>>(x, Wt, xwp);
    k_mid<<<NB, 1024, 0, stream>>>(xwp, Wt, Wk, bk, Wq, bq, bt, wqs, cb2);
    k_ta_xt<<<NB * CPB, 256, 0, stream>>>(x, wqs, cb2, xtp, stp);
    k_fin<<<NB, 1024, 0, stream>>>(xtp, stp, Wv, bv, out);
}

// Round 8
// 252.257 us; speedup vs baseline: 1.9740x; 1.0977x over previous
//
#include <hip/hip_runtime.h>

// Problem constants
#define NB 32
#define NS 2048
#define ND 512
#define NFF 512
#define SCALE 0.044194173824159216f
#define CPB 32          // chunks per batch
#define ROWS 64         // rows per chunk (CPB*ROWS = NS)

__device__ __forceinline__ float dot4(float4 a, float4 b) {
    return a.x * b.x + a.y * b.y + a.z * b.z + a.w * b.w;
}

__device__ __forceinline__ float wave_reduce(float p) {
#pragma unroll
    for (int m = 1; m < 64; m <<= 1) p += __shfl_xor(p, m, 64);
    return p;
}

// ---- K1: xwp[blk][d] = sum_{s in chunk} Wt[s]*x[b,s,d]  (pass 1) ----------
// grid = NB*CPB = 1024 blocks, 256 threads, 64 rows/block. Pure partials.
__global__ void __launch_bounds__(256) k_xw(const float* __restrict__ x,
                                            const float* __restrict__ Wt,
                                            float* __restrict__ xwp) {
    const int b = blockIdx.x >> 5;
    const int chunk = blockIdx.x & 31;
    const int s0 = chunk * ROWS;
    const int t = threadIdx.x;
    const int col = t & 127;   // float4 column
    const int half = t >> 7;   // row interleave (0/1)

    const float4* xb = (const float4*)(x + (size_t)b * NS * ND);
    float4 acc = make_float4(0.f, 0.f, 0.f, 0.f);
#pragma unroll 8
    for (int i = 0; i < 32; i++) {
        int s = s0 + half + 2 * i;
        float w = Wt[s];
        float4 v = xb[(size_t)s * 128 + col];
        acc.x += w * v.x; acc.y += w * v.y; acc.z += w * v.z; acc.w += w * v.w;
    }
    __shared__ float4 red[128];
    if (half == 1) red[col] = acc;
    __syncthreads();
    if (half == 0) {
        float4 o = red[col];
        o.x += acc.x; o.y += acc.y; o.z += acc.z; o.w += acc.w;
        ((float4*)xwp)[(size_t)blockIdx.x * 128 + col] = o;
    }
}

// ---- K2: per (batch b, group g of 64 f), 256 blocks total:
//   xw = sum_c xwp[b,c,:] (redundant per group, L2-multicast);
//   kw[f] = SCALE*(Wk[f,:].xw + bk[f]*sum(Wt)) for the 64 f of this group;
//   wqs_p[b,g,d] = sum_{f in grp} kw[f]*Wq[f,d];  cb2_p[b,g] = kw.bq (+bt g0)
// Spreads Wk/Wq reads over 8x more CUs than one-block-per-batch (per-CU L2
// bandwidth was the mid-kernel bottleneck).
__global__ void __launch_bounds__(256)
k_mid(const float* __restrict__ xwp, const float* __restrict__ Wt,
      const float* __restrict__ Wk, const float* __restrict__ bk,
      const float* __restrict__ Wq, const float* __restrict__ bq,
      const float* __restrict__ bt, float* __restrict__ wqsp,
      float* __restrict__ cb2p) {
    const int b = blockIdx.x >> 3;
    const int g = blockIdx.x & 7;
    const int t = threadIdx.x;
    const int c4 = t & 127;
    const int half = t >> 7;
    __shared__ __align__(16) float4 tmp4[256];
    __shared__ __align__(16) float sxw[ND];
    __shared__ float skw[64];
    __shared__ float sW[4];
    __shared__ float ssw;

    // Stage 1: reduce the 32 xwp chunks of batch b (each half sums 16)
    {
        const float4* xp = (const float4*)(xwp + (size_t)b * CPB * ND) + c4;
        float4 a = make_float4(0.f, 0.f, 0.f, 0.f);
#pragma unroll
        for (int c = 0; c < 16; c++) {
            float4 v = xp[(size_t)(half * 16 + c) * 128];
            a.x += v.x; a.y += v.y; a.z += v.z; a.w += v.w;
        }
        tmp4[t] = a;
    }
    if (t < 64) {   // sw = sum(Wt), wave 0, overlapped
        float s = 0.f;
#pragma unroll
        for (int i = 0; i < 32; i++) s += Wt[t + 64 * i];
        s = wave_reduce(s);
        if (t == 0) ssw = s;
    }
    __syncthreads();
    if (t < 128) {
        float4 a = tmp4[t], v = tmp4[128 + t];
        a.x += v.x; a.y += v.y; a.z += v.z; a.w += v.w;
        ((float4*)sxw)[t] = a;
    }
    __syncthreads();

    // Stage 2: 64 kw values, 4 waves x 16 f, ILP-8 reduction trees
    const int wv = t >> 6;
    const int lane = t & 63;
    const float sw = ssw;
    const float4 xa = ((const float4*)sxw)[lane];
    const float4 xc = ((const float4*)sxw)[64 + lane];
    const int fbase = g * 64;
    float cbp = 0.f;
#pragma unroll
    for (int j = 0; j < 2; j++) {
        const int f = fbase + wv * 16 + j * 8;
        float p[8];
#pragma unroll
        for (int u = 0; u < 8; u++) {
            const float4* r = (const float4*)(Wk + (size_t)(f + u) * ND);
            p[u] = dot4(xa, r[lane]) + dot4(xc, r[64 + lane]);
        }
#pragma unroll
        for (int m = 1; m < 64; m <<= 1) {
#pragma unroll
            for (int u = 0; u < 8; u++) p[u] += __shfl_xor(p[u], m, 64);
        }
        if (lane == 0) {
#pragma unroll
            for (int u = 0; u < 8; u++) {
                float k = SCALE * (p[u] + bk[f + u] * sw);
                skw[wv * 16 + j * 8 + u] = k;
                cbp += k * bq[f + u];
            }
        }
    }
    if (lane == 0) sW[wv] = cbp;
    __syncthreads();

    // Stage 3: wqs partial over this group's 64 f (coalesced over d)
    {
        const float* wp = Wq + (size_t)fbase * ND + t;
        float a0 = 0.f, a1 = 0.f;
#pragma unroll 8
        for (int j = 0; j < 64; j++) {
            float kf = skw[j];
            a0 += kf * wp[(size_t)j * ND];
            a1 += kf * wp[(size_t)j * ND + 256];
        }
        wqsp[(size_t)blockIdx.x * ND + t] = a0;
        wqsp[(size_t)blockIdx.x * ND + 256 + t] = a1;
    }
    if (t == 0) {
        float cb = sW[0] + sW[1] + sW[2] + sW[3];
        if (g == 0) cb += bt[0];
        cb2p[blockIdx.x] = cb;
    }
}

// ---- K3: ta = x.wqs + cb2; xtp[blk][d] = sum_s ta*x; stp[blk] (pass 2) ----
// grid = 1024 blocks (64 rows), 256 threads = 4 waves, 16 rows/wave.
// Head sums the 8 wqs/cb2 partials of batch b; body unchanged (proven).
__global__ void __launch_bounds__(256) k_ta_xt(const float* __restrict__ x,
                                               const float* __restrict__ wqsp,
                                               const float* __restrict__ cb2p,
                                               float* __restrict__ xtp,
                                               float* __restrict__ stp) {
    const int b = blockIdx.x >> 5;
    const int chunk = blockIdx.x & 31;
    const int wv = threadIdx.x >> 6;
    const int lane = threadIdx.x & 63;
    const float4* xb = (const float4*)(x + (size_t)b * NS * ND);

    float4 w0 = make_float4(0.f, 0.f, 0.f, 0.f);
    float4 w1 = make_float4(0.f, 0.f, 0.f, 0.f);
    float c = 0.f;
#pragma unroll
    for (int gg = 0; gg < 8; gg++) {
        const float4* wg = (const float4*)(wqsp + (size_t)(b * 8 + gg) * ND);
        float4 u0 = wg[lane];
        float4 u1 = wg[64 + lane];
        w0.x += u0.x; w0.y += u0.y; w0.z += u0.z; w0.w += u0.w;
        w1.x += u1.x; w1.y += u1.y; w1.z += u1.z; w1.w += u1.w;
        c += cb2p[b * 8 + gg];
    }

    float4 a0 = make_float4(0.f, 0.f, 0.f, 0.f);
    float4 a1 = make_float4(0.f, 0.f, 0.f, 0.f);
    float sta = 0.f;
#pragma unroll
    for (int pass = 0; pass < 2; pass++) {
        const int sbase = chunk * ROWS + wv * 16 + pass * 8;
        float4 v0[8], v1[8];
        float pd[8];
#pragma unroll
        for (int i = 0; i < 8; i++) {
            int s = sbase + i;
            v0[i] = xb[(size_t)s * 128 + lane];
            v1[i] = xb[(size_t)s * 128 + 64 + lane];
            pd[i] = dot4(v0[i], w0) + dot4(v1[i], w1);
        }
#pragma unroll
        for (int m = 1; m < 64; m <<= 1) {
#pragma unroll
            for (int i = 0; i < 8; i++) pd[i] += __shfl_xor(pd[i], m, 64);
        }
#pragma unroll
        for (int i = 0; i < 8; i++) {
            float ta = pd[i] + c;
            a0.x += ta * v0[i].x; a0.y += ta * v0[i].y;
            a0.z += ta * v0[i].z; a0.w += ta * v0[i].w;
            a1.x += ta * v1[i].x; a1.y += ta * v1[i].y;
            a1.z += ta * v1[i].z; a1.w += ta * v1[i].w;
            sta += ta;
        }
    }
    __shared__ float4 sh0[4][64];
    __shared__ float4 sh1[4][64];
    __shared__ float sW[4];
    sh0[wv][lane] = a0;
    sh1[wv][lane] = a1;
    if (lane == 0) sW[wv] = sta;
    __syncthreads();
    const int t = threadIdx.x;
    float4* dst = (float4*)xtp + (size_t)blockIdx.x * 128;
    if (t < 64) {
        float4 s0 = sh0[0][t], s1 = sh0[1][t], s2 = sh0[2][t], s3 = sh0[3][t];
        dst[t] = make_float4(s0.x + s1.x + s2.x + s3.x,
                             s0.y + s1.y + s2.y + s3.y,
                             s0.z + s1.z + s2.z + s3.z,
                             s0.w + s1.w + s2.w + s3.w);
    } else if (t < 128) {
        int l = t - 64;
        float4 s0 = sh1[0][l], s1 = sh1[1][l], s2 = sh1[2][l], s3 = sh1[3][l];
        dst[64 + l] = make_float4(s0.x + s1.x + s2.x + s3.x,
                                  s0.y + s1.y + s2.y + s3.y,
                                  s0.z + s1.z + s2.z + s3.z,
                                  s0.w + s1.w + s2.w + s3.w);
    } else if (t == 128) {
        stp[blockIdx.x] = sW[0] + sW[1] + sW[2] + sW[3];
    }
}

// ---- K4: per (batch b, group g of 64 f), 256 blocks total:
//   xt = sum_c xtp[b,c,:]; st = sum stp[b,:];
//   out[b,f] = Wv[f,:].xt + bv[f]*st for this group's 64 f
__global__ void __launch_bounds__(256)
k_fin(const float* __restrict__ xtp, const float* __restrict__ stp,
      const float* __restrict__ Wv, const float* __restrict__ bv,
      float* __restrict__ out) {
    const int b = blockIdx.x >> 3;
    const int g = blockIdx.x & 7;
    const int t = threadIdx.x;
    const int c4 = t & 127;
    const int half = t >> 7;
    __shared__ __align__(16) float4 tmp4[256];
    __shared__ __align__(16) float sxt[ND];
    __shared__ float sst;

    {
        const float4* xp = (const float4*)(xtp + (size_t)b * CPB * ND) + c4;
        float4 a = make_float4(0.f, 0.f, 0.f, 0.f);
#pragma unroll
        for (int c = 0; c < 16; c++) {
            float4 v = xp[(size_t)(half * 16 + c) * 128];
            a.x += v.x; a.y += v.y; a.z += v.z; a.w += v.w;
        }
        tmp4[t] = a;
    }
    if (t < 64) {   // st = sum of 32 chunk partials (lanes >=32 contribute 0)
        float s = (t < CPB) ? stp[b * CPB + t] : 0.f;
        s = wave_reduce(s);
        if (t == 0) sst = s;
    }
    __syncthreads();
    if (t < 128) {
        float4 a = tmp4[t], v = tmp4[128 + t];
        a.x += v.x; a.y += v.y; a.z += v.z; a.w += v.w;
        ((float4*)sxt)[t] = a;
    }
    __syncthreads();

    const int wv = t >> 6;
    const int lane = t & 63;
    const float4 xa = ((const float4*)sxt)[lane];
    const float4 xc = ((const float4*)sxt)[64 + lane];
    const float stb = sst;
#pragma unroll
    for (int j = 0; j < 2; j++) {
        const int f = g * 64 + wv * 16 + j * 8;
        float p[8];
#pragma unroll
        for (int u = 0; u < 8; u++) {
            const float4* r = (const float4*)(Wv + (size_t)(f + u) * ND);
            p[u] = dot4(xa, r[lane]) + dot4(xc, r[64 + lane]);
        }
#pragma unroll
        for (int m = 1; m < 64; m <<= 1) {
#pragma unroll
            for (int u = 0; u < 8; u++) p[u] += __shfl_xor(p[u], m, 64);
        }
        if (lane == 0) {
#pragma unroll
            for (int u = 0; u < 8; u++)
                out[b * NFF + f + u] = p[u] + bv[f + u] * stb;
        }
    }
}

extern "C" void kernel_launch(void* const* d_in, const int* in_sizes, int n_in,
                              void* d_out, int out_size, void* d_ws, size_t ws_size,
                              hipStream_t stream) {
    const float* x  = (const float*)d_in[0];
    const float* Wq = (const float*)d_in[1];
    const float* bq = (const float*)d_in[2];
    const float* Wk = (const float*)d_in[3];
    const float* bk = (const float*)d_in[4];
    const float* Wv = (const float*)d_in[5];
    const float* bv = (const float*)d_in[6];
    const float* Wt = (const float*)d_in[7];
    const float* bt = (const float*)d_in[8];
    float* out = (float*)d_out;

    float* w = (float*)d_ws;
    float* xwp  = w;                 // 1024*512 = 524288 floats
    float* xtp  = w + 524288;        // 524288
    float* stp  = w + 1048576;       // 1024
    float* wqsp = w + 1049600;       // 256*512 = 131072
    float* cb2p = w + 1180672;       // 256

    k_xw<<<NB * CPB, 256, 0, stream>>>(x, Wt, xwp);
    k_mid<<<NB * 8, 256, 0, stream>>>(xwp, Wt, Wk, bk, Wq, bq, bt, wqsp, cb2p);
    k_ta_xt<<<NB * CPB, 256, 0, stream>>>(x, wqsp, cb2p, xtp, stp);
    k_fin<<<NB * 8, 256, 0, stream>>>(xtp, stp, Wv, bv, out);
}